// Round 3
// baseline (485.280 us; speedup 1.0000x reference)
//
#include <hip/hip_runtime.h>
#include <hip/hip_bf16.h>
#include <stdint.h>

// Problem constants
#define BT     32768      // B*T rows
#define CIN    512
#define NE     640        // GROUP*ENTRY
#define ENTRY  320
#define DD     256        // COUT/GROUP
#define MROWS  64         // rows per block
#define TPB    256        // 4 waves; each wave: 64 rows x 160 cols (phase1)

using bf16x8 = __attribute__((ext_vector_type(8))) short;
using f32x4  = __attribute__((ext_vector_type(4))) float;
using u16x8  = __attribute__((ext_vector_type(8))) unsigned short;

// LDS layout (bytes)
// phase 1:  A [0,5120)  B [5120,46080)
// phase 2/3 (per 32-row half): y [0,41472)  S [41472,41600)  cb [41600,74368)
#define A_OFF   0
#define A_STR   80                 // bytes/row: 32 bf16 + pad; 2-way banks on frag reads
#define B_OFF   5120
#define Y_OFF   0
#define Y_STRE  648                // elems; 1296 B rows (16B aligned, 2-way banks)
#define Y_STRB  1296
#define S_OFF   41472
#define CB_OFF  41600
#define SMEM_BYTES 74368           // 2 blocks/CU

__device__ __forceinline__ unsigned short f2b(float f) {
    union { float f; uint32_t u; } v; v.f = f;
    uint32_t u = v.u;
    return (unsigned short)((u + 0x7FFFu + ((u >> 16) & 1u)) >> 16);
}

__device__ __forceinline__ void gl2lds16(const void* g, void* l) {
    __builtin_amdgcn_global_load_lds((const __attribute__((address_space(1))) void*)g,
                                     (__attribute__((address_space(3))) void*)l, 16, 0, 0);
}

// Prep: Wp (fp32 [640,512]) -> WpB (bf16), codebooks (fp32 [2,320,256]) -> cbT (bf16 [2,256,320])
__global__ void prep_kernel(const float* __restrict__ Wp, const float* __restrict__ cb,
                            unsigned short* __restrict__ WpB, unsigned short* __restrict__ cbT) {
    int i = blockIdx.x * blockDim.x + threadIdx.x;
    if (i < NE * CIN) {
        WpB[i] = f2b(Wp[i]);
    } else {
        int o = i - NE * CIN;
        if (o < 2 * ENTRY * DD) {
            int g = o / (DD * ENTRY);
            int r = o - g * (DD * ENTRY);
            int d = r / ENTRY;
            int e = r - d * ENTRY;
            cbT[o] = f2b(cb[(g * ENTRY + e) * DD + d]);
        }
    }
}

__global__ __launch_bounds__(TPB, 2) void fused_kernel(
    const float* __restrict__ x, const float* __restrict__ bp,
    const float* __restrict__ gum, const unsigned short* __restrict__ WpB,
    const unsigned short* __restrict__ cbT, float* __restrict__ out) {

    extern __shared__ char smem[];
    unsigned short* yS = (unsigned short*)(smem + Y_OFF);
    float*          sS = (float*)(smem + S_OFF);
    char*           aS = smem + A_OFF;
    char*           bS = smem + B_OFF;
    char*           cS = smem + CB_OFF;

    const int tid = threadIdx.x;
    const int w  = tid >> 6;     // wave 0..3
    const int l  = tid & 63;
    const int q  = l >> 4;       // quad 0..3
    const int ln = l & 15;
    const int rowbase = blockIdx.x * MROWS;

    // ---------------- Phase 1: logits = x @ Wp^T (64 rows x 640 cols) ----------------
    f32x4 acc1[4][10];
    const f32x4 fz = {0.f, 0.f, 0.f, 0.f};
#pragma unroll
    for (int rt = 0; rt < 4; ++rt)
#pragma unroll
        for (int ct = 0; ct < 10; ++ct) acc1[rt][ct] = fz;

    // A-stage: 256 threads x 8 floats = 64 rows x 32 k per iter; x prefetched 1 iter ahead
    const int ar  = tid >> 2;   // row 0..63
    const int akq = tid & 3;    // 8-float chunk
    const float* xrow = x + (size_t)(rowbase + ar) * CIN + akq * 8;
    float4 xa = *(const float4*)(xrow);
    float4 xb = *(const float4*)(xrow + 4);

#pragma unroll 1
    for (int ks = 0; ks < 16; ++ks) {
        const int k0 = ks * 32;
        // stage B (640 cols x 32 k bf16 = 2560 x 16B chunks), swizzled
#pragma unroll
        for (int i = 0; i < 10; ++i) {
            int cbase = i * 256 + (w << 6);
            int c = cbase + l;
            int e = c >> 2;
            int q2 = (c & 3) ^ ((e >> 1) & 3);
            gl2lds16(WpB + e * CIN + k0 + q2 * 8, bS + cbase * 16);
        }
        // stage A from prefetched regs
        u16x8 hv;
        hv[0] = f2b(xa.x); hv[1] = f2b(xa.y); hv[2] = f2b(xa.z); hv[3] = f2b(xa.w);
        hv[4] = f2b(xb.x); hv[5] = f2b(xb.y); hv[6] = f2b(xb.z); hv[7] = f2b(xb.w);
        *(u16x8*)(aS + ar * A_STR + akq * 16) = hv;
        if (ks < 15) {
            xa = *(const float4*)(xrow + (ks + 1) * 32);
            xb = *(const float4*)(xrow + (ks + 1) * 32 + 4);
        }
        __syncthreads();
        bf16x8 af[4];
#pragma unroll
        for (int rt = 0; rt < 4; ++rt)
            af[rt] = *(const bf16x8*)(aS + (rt * 16 + ln) * A_STR + q * 16);
#pragma unroll
        for (int g5 = 0; g5 < 2; ++g5) {
            bf16x8 bfr[5];
#pragma unroll
            for (int j = 0; j < 5; ++j) {
                int e = w * 160 + (g5 * 5 + j) * 16 + ln;
                int ch = e * 4 + (q ^ ((e >> 1) & 3));
                bfr[j] = *(const bf16x8*)(bS + ch * 16);
            }
#pragma unroll
            for (int rt = 0; rt < 4; ++rt)
#pragma unroll
                for (int j = 0; j < 5; ++j)
                    acc1[rt][g5 * 5 + j] =
                        __builtin_amdgcn_mfma_f32_16x16x32_bf16(af[rt], bfr[j], acc1[rt][g5 * 5 + j], 0, 0, 0);
        }
        __syncthreads();
    }

    float bpv[10];
#pragma unroll
    for (int ct = 0; ct < 10; ++ct) bpv[ct] = bp[w * 160 + ct * 16 + ln];

    const int g  = w >> 1;          // group (phase 3)
    const int nb = (w & 1) * 128;   // col block within group (phase 3)

    // ---------------- Two 32-row halves: softmax-exp + GEMM2 ----------------
#pragma unroll 1
    for (int h = 0; h < 2; ++h) {
        __syncthreads();                    // prior phase's LDS reads (incl. epilogue sS) done
        if (tid < 32) sS[tid] = 0.0f;
        const float* gb = gum + (size_t)(rowbase + 32 * h) * NE + w * 160 + ln;
        float gv[10];
        {
            const float* p0 = gb + (size_t)(q * 4) * NE;    // rr=0 -> row_l q*4
#pragma unroll
            for (int ct = 0; ct < 10; ++ct) gv[ct] = p0[ct * 16];
        }
        __syncthreads();                    // sS zero visible before atomics

        // ----- Phase 2 (half h): exp + row sums, y -> LDS -----
#pragma unroll
        for (int rr = 0; rr < 8; ++rr) {
            float gn[10];
            if (rr < 7) {
                int nrl = ((rr + 1) >> 2) * 16 + q * 4 + ((rr + 1) & 3);
                const float* pn = gb + (size_t)nrl * NE;
#pragma unroll
                for (int ct = 0; ct < 10; ++ct) gn[ct] = pn[ct * 16];
            }
            int rt = 2 * h + (rr >> 2);
            int r  = rr & 3;
            int row_l = (rr >> 2) * 16 + q * 4 + r;         // 0..31
            float p = 0.f;
#pragma unroll
            for (int ct = 0; ct < 10; ++ct) {
                int col = w * 160 + ct * 16 + ln;
                float v = acc1[rt][ct][r] + bpv[ct] + gv[ct];
                float e = __expf(v);
                yS[row_l * Y_STRE + col] = f2b(e);
                p += e;
            }
            p += __shfl_xor(p, 1);
            p += __shfl_xor(p, 2);
            p += __shfl_xor(p, 4);
            p += __shfl_xor(p, 8);
            if (ln == 0) atomicAdd(&sS[row_l], p);
#pragma unroll
            for (int ct = 0; ct < 10; ++ct) gv[ct] = gn[ct];
        }

        // ----- Phase 3 (half h): out = (y @ cb) / S -----
        f32x4 acc2[2][8];
#pragma unroll
        for (int rt2 = 0; rt2 < 2; ++rt2)
#pragma unroll
            for (int ct = 0; ct < 8; ++ct) acc2[rt2][ct] = fz;

#pragma unroll 1
        for (int ks = 0; ks < 10; ++ks) {
            const int k0 = ks * 32;
            // stage cb K-slice (2 groups x 256 d x 32 k = 2048 x 16B chunks), swizzled
#pragma unroll
            for (int i = 0; i < 8; ++i) {
                int cbase = i * 256 + (w << 6);
                int c = cbase + l;
                int gg = c >> 10;
                int cc = c & 1023;
                int d = cc >> 2;
                int q2 = (c & 3) ^ ((d >> 1) & 3);
                gl2lds16(cbT + (gg * DD + d) * ENTRY + k0 + q2 * 8, cS + cbase * 16);
            }
            __syncthreads();                // cb ready; (ks=0: y/S writes visible too)
            bf16x8 af2[2];
#pragma unroll
            for (int rt2 = 0; rt2 < 2; ++rt2)
                af2[rt2] = *(const bf16x8*)((char*)yS + (rt2 * 16 + ln) * Y_STRB + (g * ENTRY + k0 + q * 8) * 2);
            bf16x8 bf2[8];
#pragma unroll
            for (int ct = 0; ct < 8; ++ct) {
                int d = nb + ct * 16 + ln;
                int ch = (g << 10) + d * 4 + (q ^ ((d >> 1) & 3));
                bf2[ct] = *(const bf16x8*)(cS + ch * 16);
            }
#pragma unroll
            for (int rt2 = 0; rt2 < 2; ++rt2)
#pragma unroll
                for (int ct = 0; ct < 8; ++ct)
                    acc2[rt2][ct] = __builtin_amdgcn_mfma_f32_16x16x32_bf16(af2[rt2], bf2[ct], acc2[rt2][ct], 0, 0, 0);
            __syncthreads();                // before cb restage
        }

        // epilogue (half h)
#pragma unroll
        for (int rt2 = 0; rt2 < 2; ++rt2) {
#pragma unroll
            for (int r = 0; r < 4; ++r) {
                int row_l = rt2 * 16 + q * 4 + r;
                float inv = 1.0f / sS[row_l];
                int orow = (rowbase + 32 * h + row_l) * 512;
#pragma unroll
                for (int ct = 0; ct < 8; ++ct) {
                    int col = g * DD + nb + ct * 16 + ln;
                    out[orow + col] = acc2[rt2][ct][r] * inv;
                }
            }
        }
    }
}

extern "C" void kernel_launch(void* const* d_in, const int* in_sizes, int n_in,
                              void* d_out, int out_size, void* d_ws, size_t ws_size,
                              hipStream_t stream) {
    const float* x   = (const float*)d_in[0];
    const float* Wp  = (const float*)d_in[1];
    const float* bp  = (const float*)d_in[2];
    const float* cb  = (const float*)d_in[3];
    const float* gum = (const float*)d_in[4];
    float* out = (float*)d_out;

    unsigned short* WpB = (unsigned short*)d_ws;
    unsigned short* cbT = WpB + NE * CIN;

    int prep_total = NE * CIN + 2 * ENTRY * DD;
    prep_kernel<<<(prep_total + 255) / 256, 256, 0, stream>>>(Wp, cb, WpB, cbT);

    fused_kernel<<<dim3(BT / MROWS), dim3(TPB), SMEM_BYTES, stream>>>(x, bp, gum, WpB, cbT, out);
}

// Round 4
// 251.136 us; speedup vs baseline: 1.9323x; 1.9323x over previous
//
#include <hip/hip_runtime.h>
#include <hip/hip_bf16.h>
#include <stdint.h>

// Problem constants
#define BT     32768      // B*T rows
#define CIN    512
#define NE     640        // GROUP*ENTRY
#define ENTRY  320
#define DD     256        // COUT/GROUP
#define MROWS  64         // rows per block
#define TPB    512        // 8 waves; phase1: wave = 64 rows x 80 cols

using bf16x8 = __attribute__((ext_vector_type(8))) short;
using f32x4  = __attribute__((ext_vector_type(4))) float;
using u16x8  = __attribute__((ext_vector_type(8))) unsigned short;

// LDS layout (bytes) — x and y DISJOINT (no union -> no phase1->2 barrier)
#define X_OFF   0
#define X_STRB  1040               // 64 rows x 1040B (512 bf16 + 16B pad); 260 words %32==4 -> 2-way
#define Y_OFF   66560              // 64 rows x 1296B (640 bf16 + pad); 324 words %32==4 -> 2-way
#define Y_STRB  1296
#define Y_STRE  648
#define S_OFF   149504             // 64 fp32 row sums
#define SMEM_BYTES 149760          // 1 block/CU

__device__ __forceinline__ unsigned short f2b(float f) {
    union { float f; uint32_t u; } v; v.f = f;
    uint32_t u = v.u;
    return (unsigned short)((u + 0x7FFFu + ((u >> 16) & 1u)) >> 16);
}

// Prep: Wp (fp32 [640,512]) -> WpB (bf16), codebooks (fp32 [2,320,256]) -> cbT (bf16 [2,256,320])
__global__ void prep_kernel(const float* __restrict__ Wp, const float* __restrict__ cb,
                            unsigned short* __restrict__ WpB, unsigned short* __restrict__ cbT) {
    int i = blockIdx.x * blockDim.x + threadIdx.x;
    if (i < NE * CIN) {
        WpB[i] = f2b(Wp[i]);
    } else {
        int o = i - NE * CIN;
        if (o < 2 * ENTRY * DD) {
            int g = o / (DD * ENTRY);
            int r = o - g * (DD * ENTRY);
            int d = r / ENTRY;
            int e = r - d * ENTRY;
            cbT[o] = f2b(cb[(g * ENTRY + e) * DD + d]);
        }
    }
}

__global__ __launch_bounds__(TPB, 2) void fused_kernel(
    const float* __restrict__ x, const float* __restrict__ bp,
    const float* __restrict__ gum, const unsigned short* __restrict__ WpB,
    const unsigned short* __restrict__ cbT, float* __restrict__ out) {

    extern __shared__ char smem[];
    unsigned short* yS = (unsigned short*)(smem + Y_OFF);
    float*          sS = (float*)(smem + S_OFF);

    const int tid = threadIdx.x;
    const int w  = tid >> 6;     // wave 0..7
    const int l  = tid & 63;
    const int q  = l >> 4;       // quad 0..3
    const int ln = l & 15;
    const int rowbase = blockIdx.x * MROWS;

    if (tid < MROWS) sS[tid] = 0.0f;

    // ---- stage full x tile: 64 rows x 512 K, fp32 -> bf16 -> LDS (once) ----
#pragma unroll
    for (int i = 0; i < 8; ++i) {
        int c   = tid + i * TPB;          // 0..4095 chunks of 8 floats
        int row = c >> 6;
        int c8  = c & 63;
        const float* p = x + (size_t)(rowbase + row) * CIN + c8 * 8;
        float4 a = *(const float4*)p;
        float4 b = *(const float4*)(p + 4);
        u16x8 hv;
        hv[0] = f2b(a.x); hv[1] = f2b(a.y); hv[2] = f2b(a.z); hv[3] = f2b(a.w);
        hv[4] = f2b(b.x); hv[5] = f2b(b.y); hv[6] = f2b(b.z); hv[7] = f2b(b.w);
        *(u16x8*)(smem + X_OFF + row * X_STRB + c8 * 16) = hv;
    }

    // gumbel prefetch for first phase-2 row (independent of everything)
    const float* gbase = gum + (size_t)rowbase * NE + w * 80 + ln;
    float gv[5];
#pragma unroll
    for (int j = 0; j < 5; ++j) gv[j] = gbase[(size_t)(q * 4) * NE + j * 16];

    // ---------------- Phase 1: logits = x @ Wp^T, B direct from global ----------------
    f32x4 acc1[4][5];
    const f32x4 fz = {0.f, 0.f, 0.f, 0.f};
#pragma unroll
    for (int rt = 0; rt < 4; ++rt)
#pragma unroll
        for (int j = 0; j < 5; ++j) acc1[rt][j] = fz;

    // lane's B fragment base: col e = w*80 + j*16 + ln, k = k0 + q*8
    const unsigned short* bp1 = WpB + (size_t)(w * 80 + ln) * CIN + q * 8;
    bf16x8 bc[5], bn[5];
#pragma unroll
    for (int j = 0; j < 5; ++j) bc[j] = *(const bf16x8*)(bp1 + (size_t)j * 16 * CIN);

    __syncthreads();   // x tile (and sS init) visible

#pragma unroll 1
    for (int ks = 0; ks < 16; ++ks) {
        const int k0 = ks * 32;
        if (ks < 15) {
#pragma unroll
            for (int j = 0; j < 5; ++j)
                bn[j] = *(const bf16x8*)(bp1 + (size_t)j * 16 * CIN + k0 + 32);
        }
        bf16x8 af[4];
#pragma unroll
        for (int rt = 0; rt < 4; ++rt)
            af[rt] = *(const bf16x8*)(smem + X_OFF + (rt * 16 + ln) * X_STRB + (k0 + q * 8) * 2);
#pragma unroll
        for (int j = 0; j < 5; ++j)
#pragma unroll
            for (int rt = 0; rt < 4; ++rt)
                acc1[rt][j] = __builtin_amdgcn_mfma_f32_16x16x32_bf16(af[rt], bc[j], acc1[rt][j], 0, 0, 0);
        if (ks < 15) {
#pragma unroll
            for (int j = 0; j < 5; ++j) bc[j] = bn[j];
        }
    }

    // ---------------- Phase 2: exp + row sums -> y LDS (no barrier needed before) ----------------
    float bpv[5];
#pragma unroll
    for (int j = 0; j < 5; ++j) bpv[j] = bp[w * 80 + j * 16 + ln];

#pragma unroll
    for (int ri = 0; ri < 16; ++ri) {
        float gn[5];
        if (ri < 15) {
            int nrow = ((ri + 1) >> 2) * 16 + q * 4 + ((ri + 1) & 3);
            const float* pn = gbase + (size_t)nrow * NE;
#pragma unroll
            for (int j = 0; j < 5; ++j) gn[j] = pn[j * 16];
        }
        const int rt = ri >> 2, r = ri & 3;
        const int row = rt * 16 + q * 4 + r;
        float p = 0.f;
#pragma unroll
        for (int j = 0; j < 5; ++j) {
            float v = acc1[rt][j][r] + bpv[j] + gv[j];
            float e = __expf(v);
            yS[row * Y_STRE + w * 80 + j * 16 + ln] = f2b(e);
            p += e;
        }
        p += __shfl_xor(p, 1);
        p += __shfl_xor(p, 2);
        p += __shfl_xor(p, 4);
        p += __shfl_xor(p, 8);
        if (ln == 0) atomicAdd(&sS[row], p);
#pragma unroll
        for (int j = 0; j < 5; ++j) gv[j] = gn[j];
    }

    // ---------------- Phase 3: out = (y @ cb) / S, cb direct from global ----------------
    const int g   = w >> 2;          // group (4 waves each)
    const int nbp = (w & 3) * 64;    // col block within group

    f32x4 acc2[4][4];
#pragma unroll
    for (int rt = 0; rt < 4; ++rt)
#pragma unroll
        for (int ct = 0; ct < 4; ++ct) acc2[rt][ct] = fz;

    const unsigned short* cp = cbT + (size_t)(g * DD + nbp + ln) * ENTRY + q * 8;
    bf16x8 cc[4], cn[4];
#pragma unroll
    for (int ct = 0; ct < 4; ++ct) cc[ct] = *(const bf16x8*)(cp + (size_t)ct * 16 * ENTRY);

    __syncthreads();   // all y writes + row-sum atomics complete

#pragma unroll 1
    for (int ks = 0; ks < 10; ++ks) {
        const int k0 = ks * 32;
        if (ks < 9) {
#pragma unroll
            for (int ct = 0; ct < 4; ++ct)
                cn[ct] = *(const bf16x8*)(cp + (size_t)ct * 16 * ENTRY + k0 + 32);
        }
        bf16x8 af2[4];
#pragma unroll
        for (int rt = 0; rt < 4; ++rt)
            af2[rt] = *(const bf16x8*)(smem + Y_OFF + (rt * 16 + ln) * Y_STRB + (g * ENTRY + k0 + q * 8) * 2);
#pragma unroll
        for (int ct = 0; ct < 4; ++ct)
#pragma unroll
            for (int rt = 0; rt < 4; ++rt)
                acc2[rt][ct] = __builtin_amdgcn_mfma_f32_16x16x32_bf16(af2[rt], cc[ct], acc2[rt][ct], 0, 0, 0);
        if (ks < 9) {
#pragma unroll
            for (int ct = 0; ct < 4; ++ct) cc[ct] = cn[ct];
        }
    }

    // epilogue: divide by softmax denom, store fp32
#pragma unroll
    for (int rt = 0; rt < 4; ++rt) {
#pragma unroll
        for (int r = 0; r < 4; ++r) {
            const int row = rt * 16 + q * 4 + r;
            const float inv = 1.0f / sS[row];
            float* op = out + (size_t)(rowbase + row) * 512 + g * DD + nbp + ln;
#pragma unroll
            for (int ct = 0; ct < 4; ++ct)
                op[ct * 16] = acc2[rt][ct][r] * inv;
        }
    }
}

extern "C" void kernel_launch(void* const* d_in, const int* in_sizes, int n_in,
                              void* d_out, int out_size, void* d_ws, size_t ws_size,
                              hipStream_t stream) {
    const float* x   = (const float*)d_in[0];
    const float* Wp  = (const float*)d_in[1];
    const float* bp  = (const float*)d_in[2];
    const float* cb  = (const float*)d_in[3];
    const float* gum = (const float*)d_in[4];
    float* out = (float*)d_out;

    unsigned short* WpB = (unsigned short*)d_ws;
    unsigned short* cbT = WpB + NE * CIN;

    int prep_total = NE * CIN + 2 * ENTRY * DD;
    prep_kernel<<<(prep_total + 255) / 256, 256, 0, stream>>>(Wp, cb, WpB, cbT);

    fused_kernel<<<dim3(BT / MROWS), dim3(TPB), SMEM_BYTES, stream>>>(x, bp, gum, WpB, cbT, out);
}